// Round 6
// baseline (628.225 us; speedup 1.0000x reference)
//
#include <hip/hip_runtime.h>
#include <math.h>

// ---------------------------------------------------------------------------
// GCN 2-layer: out = log_softmax( Ahat @ relu(Ahat @ (X W1) + b1) @ W2 + b2 )
// Round 13: gemm1 occupancy fix. r12 counters unmasked gemm1_k at 121.8us,
// latency-bound: grid 782 blocks -> 3 blocks/CU -> 12 waves/CU (34% occ),
// all pipes <35% busy. Fix: 2-way K-split (each tile computed by 2 blocks,
// K=[0,256) and [256,512)), f32 atomicAdd partials into zeroed xwf buffer
// -> grid 1564 -> ~24 waves/CU (75%). Exactly 2 commutative fp32 adds per
// output = deterministic. dinv*bf16 pack moved to tiny pack_k epilogue.
// Everything else identical to round 12 (496.7us).
// ---------------------------------------------------------------------------

#define DIM 32
#define NCLS 40
#define F_IN 512
#define BSH 8            // bucket = dst >> 8 (256 nodes/bucket)
#define EPB 8192         // edges per block in part
#define LMAX 9216        // slots per bucket (mean 8192 + 11 sigma)

// ---- bf16 helpers (RNE pack, exact unpack) ----
__device__ __forceinline__ unsigned int bf16rne(float x) {
    unsigned int u = __float_as_uint(x);
    return (u + 0x7fffu + ((u >> 16) & 1u)) >> 16;
}
__device__ __forceinline__ unsigned int packpair(float lo, float hi) {
    return bf16rne(lo) | (bf16rne(hi) << 16);
}
__device__ __forceinline__ void unpack8(uint4 u, float* f) {
    f[0] = __uint_as_float(u.x << 16);
    f[1] = __uint_as_float(u.x & 0xffff0000u);
    f[2] = __uint_as_float(u.y << 16);
    f[3] = __uint_as_float(u.y & 0xffff0000u);
    f[4] = __uint_as_float(u.z << 16);
    f[5] = __uint_as_float(u.z & 0xffff0000u);
    f[6] = __uint_as_float(u.w << 16);
    f[7] = __uint_as_float(u.w & 0xffff0000u);
}

// ---------------- K0: init bucket cursors to fixed-stride bases ----------
__global__ __launch_bounds__(256) void initcur_k(int* __restrict__ gcur) {
    int t = blockIdx.x * 256 + threadIdx.x;
    if (t < 512) gcur[t] = t * LMAX;
}

// ---------------- K1: partition into fixed-stride buckets ----------------
__global__ __launch_bounds__(256) void part_k(const int* __restrict__ src,
                                              const int* __restrict__ dst,
                                              int* __restrict__ gcur,
                                              int* __restrict__ pairs, int E) {
    __shared__ int st[EPB];     // staged dst values
    __shared__ int h[512];
    __shared__ int hb[512];
    int tid = threadIdx.x;
    h[tid] = 0; h[tid + 256] = 0;
    __syncthreads();
    int base = blockIdx.x * EPB;
#pragma unroll 4
    for (int k = 0; k < EPB / 256; ++k) {
        int e = base + k * 256 + tid;
        if (e < E) {
            int d = dst[e];
            st[k * 256 + tid] = d;
            atomicAdd(&h[d >> BSH], 1);
        }
    }
    __syncthreads();
    for (int b = tid; b < 512; b += 256) {
        int cnt = h[b];
        hb[b] = cnt ? atomicAdd(&gcur[b], cnt) : 0;
        h[b] = 0;  // reuse as running offset
    }
    __syncthreads();
#pragma unroll 4
    for (int k = 0; k < EPB / 256; ++k) {
        int e = base + k * 256 + tid;
        if (e < E) {
            int d = st[k * 256 + tid];
            int b = d >> BSH;
            int r = atomicAdd(&h[b], 1);
            pairs[hb[b] + r] = ((d & 255) << 17) | src[e];   // src < 2^17
        }
    }
}

// ---------------- K2: per-bucket CSR build + per-node src-region sort ------
__global__ __launch_bounds__(256) void build_k(const int* __restrict__ pairs,
                                               const int* __restrict__ gcur,
                                               int* __restrict__ rowptr,
                                               int* __restrict__ rowcnt,
                                               int* __restrict__ csr,
                                               float* __restrict__ dinv,
                                               int n) {
    __shared__ int lcsr[LMAX];           // 36.9 KB
    __shared__ int bins[256 * 17];       // 17.4 KB, stride 17 vs bank conflicts
    __shared__ int cnt[256];
    __shared__ int sc[256];
    __shared__ int cur[256];
    int tid = threadIdx.x;
    int b = blockIdx.x;
    int lo = b * LMAX;
    int cb = gcur[b] - lo;               // final cursor = base + count
    if (cb > LMAX) cb = LMAX;            // statistically never clamps
    cnt[tid] = 0;
    __syncthreads();
    const int* Pb = pairs + lo;
    for (int i = tid; i < cb; i += 256)
        atomicAdd(&cnt[Pb[i] >> 17], 1);
    __syncthreads();
    int c = cnt[tid];
    sc[tid] = c;
    __syncthreads();
    for (int off = 1; off < 256; off <<= 1) {
        int v = sc[tid];
        if (tid >= off) v += sc[tid - off];
        __syncthreads();
        sc[tid] = v;
        __syncthreads();
    }
    int excl = sc[tid] - c;
    int v = (b << BSH) + tid;
    if (v < n) {
        rowptr[v] = lo + excl;
        rowcnt[v] = c;
        dinv[v] = rsqrtf((float)(c + 1));   // +1 self loop
    }
    cur[tid] = excl;                        // bucket-local cursor
    __syncthreads();
    for (int i = tid; i < cb; i += 256) {
        int p = Pb[i];
        int pos = atomicAdd(&cur[p >> 17], 1);
        lcsr[pos] = p & 0x1FFFF;
    }
    __syncthreads();
    // per-node 16-bin counting sort by src>>13 (one thread per node)
    {
        int* mb = &bins[tid * 17];
        int s = excl, e = excl + c;
#pragma unroll
        for (int k = 0; k < 16; ++k) mb[k] = 0;
        for (int i = s; i < e; ++i) ++mb[lcsr[i] >> 13];
        int run = s;
#pragma unroll
        for (int k = 0; k < 16; ++k) { int q = mb[k]; mb[k] = run; run += q; }
        for (int i = s; i < e; ++i) {
            int val = lcsr[i];
            int k = val >> 13;
            int pos = mb[k]++;
            csr[lo + pos] = val;
        }
    }
}

// ---------------- GEMM1: 4x4 micro-tile, 2-way K-split, f32 atomic out ----
#define GR 128
__global__ __launch_bounds__(256) void gemm1_k(const float* __restrict__ x,
                                               const float* __restrict__ W1,
                                               float* __restrict__ xwf, int n) {
    __shared__ float xs[32 * GR];   // [kk][row], 16 KB
    __shared__ float ws[32 * 32];   // [kk][col], 4 KB
    int tid = threadIdx.x;
    int tile = blockIdx.x >> 1;
    int kh = blockIdx.x & 1;       // K half: [kh*256, kh*256+256)
    int base = tile * GR;
    int rg = tid & 31;        // rows 4rg..4rg+3
    int cg = tid >> 5;        // cols 4cg..4cg+3
    float acc[4][4];
#pragma unroll
    for (int i = 0; i < 4; ++i)
#pragma unroll
        for (int j = 0; j < 4; ++j) acc[i][j] = 0.f;

    int lr = tid >> 1;        // staging row 0..127
    int lq = tid & 1;         // k half within tile
    int grow = base + lr;
    if (grow >= n) grow = n - 1;
    const float* xrow = x + (size_t)grow * F_IN;
    int wk = tid >> 3;        // 0..31
    int wc = tid & 7;         // 0..7

    int kbeg = kh * 256, kend = kbeg + 256;
    for (int k0 = kbeg; k0 < kend; k0 += 32) {
        float4 a[4];
#pragma unroll
        for (int j = 0; j < 4; ++j)
            a[j] = *(const float4*)(xrow + k0 + lq * 16 + j * 4);
        float4 wv = *(const float4*)(W1 + (size_t)(k0 + wk) * DIM + wc * 4);
        __syncthreads();
#pragma unroll
        for (int j = 0; j < 4; ++j) {
            xs[(lq * 16 + j * 4 + 0) * GR + lr] = a[j].x;
            xs[(lq * 16 + j * 4 + 1) * GR + lr] = a[j].y;
            xs[(lq * 16 + j * 4 + 2) * GR + lr] = a[j].z;
            xs[(lq * 16 + j * 4 + 3) * GR + lr] = a[j].w;
        }
        *(float4*)&ws[wk * 32 + wc * 4] = wv;
        __syncthreads();
#pragma unroll 8
        for (int kk = 0; kk < 32; ++kk) {
            float4 xv = *(const float4*)&xs[kk * GR + rg * 4];
            float4 wv2 = *(const float4*)&ws[kk * 32 + cg * 4];
            acc[0][0] = fmaf(xv.x, wv2.x, acc[0][0]);
            acc[0][1] = fmaf(xv.x, wv2.y, acc[0][1]);
            acc[0][2] = fmaf(xv.x, wv2.z, acc[0][2]);
            acc[0][3] = fmaf(xv.x, wv2.w, acc[0][3]);
            acc[1][0] = fmaf(xv.y, wv2.x, acc[1][0]);
            acc[1][1] = fmaf(xv.y, wv2.y, acc[1][1]);
            acc[1][2] = fmaf(xv.y, wv2.z, acc[1][2]);
            acc[1][3] = fmaf(xv.y, wv2.w, acc[1][3]);
            acc[2][0] = fmaf(xv.z, wv2.x, acc[2][0]);
            acc[2][1] = fmaf(xv.z, wv2.y, acc[2][1]);
            acc[2][2] = fmaf(xv.z, wv2.z, acc[2][2]);
            acc[2][3] = fmaf(xv.z, wv2.w, acc[2][3]);
            acc[3][0] = fmaf(xv.w, wv2.x, acc[3][0]);
            acc[3][1] = fmaf(xv.w, wv2.y, acc[3][1]);
            acc[3][2] = fmaf(xv.w, wv2.z, acc[3][2]);
            acc[3][3] = fmaf(xv.w, wv2.w, acc[3][3]);
        }
    }
#pragma unroll
    for (int i = 0; i < 4; ++i) {
        int row = base + rg * 4 + i;
        if (row < n) {
            float* o = xwf + (size_t)row * DIM + cg * 4;
#pragma unroll
            for (int j = 0; j < 4; ++j) atomicAdd(&o[j], acc[i][j]);
        }
    }
}

// ---------------- pack: xwp = bf16(xwf * dinv) ----------------------------
__global__ __launch_bounds__(256) void pack_k(const float* __restrict__ xwf,
                                              const float* __restrict__ dinv,
                                              unsigned short* __restrict__ xwp, int n) {
    int t = blockIdx.x * 256 + threadIdx.x;
    int v = t >> 2;
    int f8 = t & 3;
    if (v >= n) return;
    const float4* p = (const float4*)(xwf + (size_t)v * DIM + f8 * 8);
    float4 p0 = p[0], p1 = p[1];
    float dv = dinv[v];
    uint4 o;
    o.x = packpair(p0.x * dv, p0.y * dv);
    o.y = packpair(p0.z * dv, p0.w * dv);
    o.z = packpair(p1.x * dv, p1.y * dv);
    o.w = packpair(p1.z * dv, p1.w * dv);
    *(uint4*)(xwp + (size_t)v * DIM + f8 * 8) = o;
}

// ---- shared 8-deep gather-accumulate body (8 loads in flight) ----
__device__ __forceinline__ void gather_accum(const uint4* __restrict__ F,
                                             const int* __restrict__ csr,
                                             int e, int end, int f8, float* s) {
    float tmp[8];
    for (; e + 7 < end; e += 8) {
        uint4 a0 = F[(size_t)csr[e]     * 4 + f8];
        uint4 a1 = F[(size_t)csr[e + 1] * 4 + f8];
        uint4 a2 = F[(size_t)csr[e + 2] * 4 + f8];
        uint4 a3 = F[(size_t)csr[e + 3] * 4 + f8];
        uint4 a4 = F[(size_t)csr[e + 4] * 4 + f8];
        uint4 a5 = F[(size_t)csr[e + 5] * 4 + f8];
        uint4 a6 = F[(size_t)csr[e + 6] * 4 + f8];
        uint4 a7 = F[(size_t)csr[e + 7] * 4 + f8];
        unpack8(a0, tmp);
#pragma unroll
        for (int j = 0; j < 8; ++j) s[j] += tmp[j];
        unpack8(a1, tmp);
#pragma unroll
        for (int j = 0; j < 8; ++j) s[j] += tmp[j];
        unpack8(a2, tmp);
#pragma unroll
        for (int j = 0; j < 8; ++j) s[j] += tmp[j];
        unpack8(a3, tmp);
#pragma unroll
        for (int j = 0; j < 8; ++j) s[j] += tmp[j];
        unpack8(a4, tmp);
#pragma unroll
        for (int j = 0; j < 8; ++j) s[j] += tmp[j];
        unpack8(a5, tmp);
#pragma unroll
        for (int j = 0; j < 8; ++j) s[j] += tmp[j];
        unpack8(a6, tmp);
#pragma unroll
        for (int j = 0; j < 8; ++j) s[j] += tmp[j];
        unpack8(a7, tmp);
#pragma unroll
        for (int j = 0; j < 8; ++j) s[j] += tmp[j];
    }
    for (; e + 3 < end; e += 4) {
        uint4 a0 = F[(size_t)csr[e]     * 4 + f8];
        uint4 a1 = F[(size_t)csr[e + 1] * 4 + f8];
        uint4 a2 = F[(size_t)csr[e + 2] * 4 + f8];
        uint4 a3 = F[(size_t)csr[e + 3] * 4 + f8];
        unpack8(a0, tmp);
#pragma unroll
        for (int j = 0; j < 8; ++j) s[j] += tmp[j];
        unpack8(a1, tmp);
#pragma unroll
        for (int j = 0; j < 8; ++j) s[j] += tmp[j];
        unpack8(a2, tmp);
#pragma unroll
        for (int j = 0; j < 8; ++j) s[j] += tmp[j];
        unpack8(a3, tmp);
#pragma unroll
        for (int j = 0; j < 8; ++j) s[j] += tmp[j];
    }
    for (; e < end; ++e) {
        unpack8(F[(size_t)csr[e] * 4 + f8], tmp);
#pragma unroll
        for (int j = 0; j < 8; ++j) s[j] += tmp[j];
    }
}

// ---------------- agg1: hts = bf16( relu(agg*dinv + b1) * dinv ) ----------
__global__ __launch_bounds__(256) void agg1_k(const uint4* __restrict__ F,
                                              const int* __restrict__ rowptr,
                                              const int* __restrict__ rowcnt,
                                              const int* __restrict__ csr,
                                              const float* __restrict__ dinv,
                                              const float* __restrict__ bias,
                                              uint4* __restrict__ out, int n) {
    int t = blockIdx.x * 256 + threadIdx.x;
    int v = t >> 2;
    int f8 = t & 3;
    if (v >= n) return;
    float s[8];
    unpack8(F[(size_t)v * 4 + f8], s);   // self-loop (already *dinv)
    int e = rowptr[v];
    gather_accum(F, csr, e, e + rowcnt[v], f8, s);
    float dv = dinv[v];
    float4 b0 = *(const float4*)(bias + f8 * 8);
    float4 b1 = *(const float4*)(bias + f8 * 8 + 4);
    float bb[8] = {b0.x, b0.y, b0.z, b0.w, b1.x, b1.y, b1.z, b1.w};
    float r[8];
#pragma unroll
    for (int j = 0; j < 8; ++j) r[j] = fmaxf(s[j] * dv + bb[j], 0.f) * dv;
    uint4 o;
    o.x = packpair(r[0], r[1]);
    o.y = packpair(r[2], r[3]);
    o.z = packpair(r[4], r[5]);
    o.w = packpair(r[6], r[7]);
    out[(size_t)v * 4 + f8] = o;
}

// ---------------- fused agg2 + (a2 @ W2 + b2) + log_softmax ----------------
__global__ __launch_bounds__(256) void agg2final_k(const uint4* __restrict__ F,
                                                   const int* __restrict__ rowptr,
                                                   const int* __restrict__ rowcnt,
                                                   const int* __restrict__ csr,
                                                   const float* __restrict__ dinv,
                                                   const float* __restrict__ W2,
                                                   const float* __restrict__ b2,
                                                   float* __restrict__ out, int n) {
    __shared__ float w2s[DIM * NCLS];   // 1280 floats
    __shared__ float b2s[NCLS];
    __shared__ float a2s[64 * 33];      // 64 nodes x 32 feats, pad 33
    int tid = threadIdx.x;
    for (int i = tid; i < DIM * NCLS; i += 256) w2s[i] = W2[i];
    if (tid < NCLS) b2s[tid] = b2[tid];

    int nl = tid >> 2;       // node-local 0..63
    int f8 = tid & 3;
    int v = blockIdx.x * 64 + nl;
    if (v < n) {
        float s[8];
        unpack8(F[(size_t)v * 4 + f8], s);
        int e = rowptr[v];
        gather_accum(F, csr, e, e + rowcnt[v], f8, s);
        float dv = dinv[v];
#pragma unroll
        for (int j = 0; j < 8; ++j) a2s[nl * 33 + f8 * 8 + j] = s[j] * dv;
    }
    __syncthreads();

    // phase B: each thread computes 10 classes for its node
    int q = f8;              // classes q*10 .. q*10+9
    float lg[10];
#pragma unroll
    for (int c = 0; c < 10; ++c) lg[c] = b2s[q * 10 + c];
#pragma unroll
    for (int k = 0; k < DIM; ++k) {
        float a = a2s[nl * 33 + k];
        const float* wr = &w2s[k * NCLS + q * 10];
#pragma unroll
        for (int c = 0; c < 10; ++c) lg[c] += a * wr[c];
    }
    float m = lg[0];
#pragma unroll
    for (int c = 1; c < 10; ++c) m = fmaxf(m, lg[c]);
    m = fmaxf(m, __shfl_xor(m, 1));
    m = fmaxf(m, __shfl_xor(m, 2));
    float ssum = 0.f;
#pragma unroll
    for (int c = 0; c < 10; ++c) ssum += __expf(lg[c] - m);
    ssum += __shfl_xor(ssum, 1);
    ssum += __shfl_xor(ssum, 2);
    float lse = m + __logf(ssum);
    if (v < n) {
        float* o = out + (size_t)v * NCLS + q * 10;
#pragma unroll
        for (int c = 0; c < 10; ++c) o[c] = lg[c] - lse;
    }
}

// ---------------------------------------------------------------------------
extern "C" void kernel_launch(void* const* d_in, const int* in_sizes, int n_in,
                              void* d_out, int out_size, void* d_ws, size_t ws_size,
                              hipStream_t stream) {
    const float* x  = (const float*)d_in[0];
    const int*   ei = (const int*)d_in[1];
    const float* W1 = (const float*)d_in[2];
    const float* b1 = (const float*)d_in[3];
    const float* W2 = (const float*)d_in[4];
    const float* b2 = (const float*)d_in[5];
    float* out = (float*)d_out;

    int n = in_sizes[0] / F_IN;   // 100000
    int E = in_sizes[1] / 2;      // 3200000
    const int* src = ei;
    const int* dst = ei + E;
    int nbk = (n + 255) >> BSH;   // 391 (<=512)
    size_t padE = (size_t)nbk * LMAX;   // padded slots (14.4 MB as int)

    // workspace layout (256B aligned)
    char* w = (char*)d_ws;
    size_t off = 0;
    auto alloc = [&](size_t bytes) -> void* {
        void* p = w + off;
        off += (bytes + 255) & ~(size_t)255;
        return p;
    };
    size_t featB2 = ((size_t)n * DIM * 2 + 255) & ~(size_t)255;  // 6.4 MB bf16
    int*   csr    = (int*)alloc(padE * 4);          // 14.4 MB padded
    char*  pairsR = (char*)alloc(padE * 4);         // 14.4 MB (aliased below)
    int*   rowptr = (int*)alloc((size_t)n * 4);
    int*   rowcnt = (int*)alloc((size_t)n * 4);
    float* dinv   = (float*)alloc((size_t)n * 4);
    int*   gcur   = (int*)alloc(512 * 4);
    float* xwf    = (float*)alloc((size_t)n * DIM * 4);  // 12.8 MB f32 partials
    (void)ws_size;

    int*            pairs = (int*)pairsR;                // live: part..build
    unsigned short* xwp   = (unsigned short*)pairsR;     // live: pack..agg1
    unsigned short* hts   = (unsigned short*)(pairsR + featB2); // live: agg1..agg2

    int nebk = (E + EPB - 1) / EPB;   // 391
    int ntile = (n + GR - 1) / GR;    // 782

    hipMemsetAsync(xwf, 0, (size_t)n * DIM * 4, stream);
    initcur_k<<<2, 256, 0, stream>>>(gcur);
    part_k <<<nebk, 256, 0, stream>>>(src, dst, gcur, pairs, E);
    build_k<<<nbk, 256, 0, stream>>>(pairs, gcur, rowptr, rowcnt, csr, dinv, n);

    gemm1_k<<<ntile * 2, 256, 0, stream>>>(x, W1, xwf, n);
    pack_k <<<((size_t)n * 4 + 255) / 256, 256, 0, stream>>>(xwf, dinv, xwp, n);
    agg1_k<<<((size_t)n * 4 + 255) / 256, 256, 0, stream>>>(
        (const uint4*)xwp, rowptr, rowcnt, csr, dinv, b1, (uint4*)hts, n);
    agg2final_k<<<(n + 63) / 64, 256, 0, stream>>>(
        (const uint4*)hts, rowptr, rowcnt, csr, dinv, W2, b2, out, n);
}